// Round 1
// baseline (2005.615 us; speedup 1.0000x reference)
//
#include <hip/hip_runtime.h>
#include <hip/hip_bf16.h>

// LatentRecurrent: B=4096, Z=512, H=384, T=32, r = 0.2*4/32 = 0.025
// Per step t=1..31:
//   temp = [lrelu(z@W1^T+b1), h]            (K1 writes cols 0..383; h-part maintained)
//   zn = lrelu(temp@W2^T+b2)*r + z          (K2, N-cols 0..511)
//   hn = lrelu(temp@W3^T+b3)*r + h          (K2, N-cols 512..895)
//   out[b,t,:] = zn - z0
// out[b,0,:] = 0.

typedef __bf16 bf16x8 __attribute__((ext_vector_type(8)));
typedef float f32x4 __attribute__((ext_vector_type(4)));

#define B_ROWS 4096
#define ZDIM 512
#define HDIM 384
#define TFRAMES 32

__device__ __forceinline__ void load16(const void* g, void* s) {
    __builtin_amdgcn_global_load_lds(
        (const __attribute__((address_space(1))) void*)g,
        (__attribute__((address_space(3))) void*)s, 16, 0, 0);
}

__device__ __forceinline__ float lrelu(float x) { return x >= 0.f ? x : 0.01f * x; }

// ---------------- K1: temp[:, 0:384] = bf16(lrelu(zb @ W1^T + b1)) ----------------
// BM=64, BN=128, BK=64, 4 waves (2x2), wave tile 32x64 (2x4 MFMA tiles)
__global__ __launch_bounds__(256) void k1_gemm(
    const __hip_bfloat16* __restrict__ A,   // zb [4096,512]
    const __hip_bfloat16* __restrict__ W,   // W1b [384,512]
    const float* __restrict__ bias,         // b1
    __hip_bfloat16* __restrict__ T)         // temp buffer [4096,768]
{
    constexpr int BM = 64, BN = 128, BK = 64, K = 512, LDA = 512, LDW = 512, LDT = 768;
    __shared__ __hip_bfloat16 As[BM * BK];
    __shared__ __hip_bfloat16 Bs[BN * BK];
    const int tid = threadIdx.x;
    const int w = tid >> 6, l = tid & 63;
    const int wm = w >> 1, wn = w & 1;
    const int m0 = blockIdx.y * BM, n0 = blockIdx.x * BN;
    const int lrow = l >> 3, lcol = (l & 7) * 8;

    f32x4 acc[2][4] = {};

    for (int kb = 0; kb < K; kb += BK) {
        __syncthreads();
        #pragma unroll
        for (int i = 0; i < BM / 32; ++i) {
            int p = w * (BM / 32) + i;
            int rr = p * 8 + lrow;
            load16(A + (size_t)(m0 + rr) * LDA + kb + lcol, As + rr * BK + lcol);
        }
        #pragma unroll
        for (int i = 0; i < BN / 32; ++i) {
            int p = w * (BN / 32) + i;
            int rr = p * 8 + lrow;
            load16(W + (size_t)(n0 + rr) * LDW + kb + lcol, Bs + rr * BK + lcol);
        }
        __builtin_amdgcn_s_waitcnt(0);
        __syncthreads();
        #pragma unroll
        for (int ks = 0; ks < BK; ks += 32) {
            bf16x8 af[2], bfr[4];
            #pragma unroll
            for (int i = 0; i < 2; ++i)
                af[i] = *(const bf16x8*)(const void*)(As + (wm * 32 + i * 16 + (l & 15)) * BK + ks + (l >> 4) * 8);
            #pragma unroll
            for (int j = 0; j < 4; ++j)
                bfr[j] = *(const bf16x8*)(const void*)(Bs + (wn * 64 + j * 16 + (l & 15)) * BK + ks + (l >> 4) * 8);
            #pragma unroll
            for (int i = 0; i < 2; ++i)
                #pragma unroll
                for (int j = 0; j < 4; ++j)
                    acc[i][j] = __builtin_amdgcn_mfma_f32_16x16x32_bf16(af[i], bfr[j], acc[i][j], 0, 0, 0);
        }
    }
    #pragma unroll
    for (int j = 0; j < 4; ++j) {
        int col = n0 + wn * 64 + j * 16 + (l & 15);
        float bv = bias[col];
        #pragma unroll
        for (int i = 0; i < 2; ++i) {
            int rbase = m0 + wm * 32 + i * 16 + (l >> 4) * 4;
            #pragma unroll
            for (int rg = 0; rg < 4; ++rg) {
                float v = lrelu(acc[i][j][rg] + bv);
                T[(size_t)(rbase + rg) * LDT + col] = __float2bfloat16(v);
            }
        }
    }
}

// ---------------- K2: fused GEMM2+GEMM3 + state update + out write ----------------
// BM=128, BN=128, BK=64, 4 waves (2x2), wave tile 64x64 (4x4 MFMA tiles)
// N-tiles 0..3 -> W2 (z update), 4..6 -> W3 (h update)
__global__ __launch_bounds__(256) void k2_gemm(
    const __hip_bfloat16* __restrict__ A,    // temp_cur [4096,768]
    const __hip_bfloat16* __restrict__ W2b,  // [512,768]
    const __hip_bfloat16* __restrict__ W3b,  // [384,768]
    const float* __restrict__ b2, const float* __restrict__ b3,
    float* __restrict__ zs, float* __restrict__ hs,
    __hip_bfloat16* __restrict__ zb, __hip_bfloat16* __restrict__ tnext,
    const float* __restrict__ z0, float* __restrict__ out, int t)
{
    constexpr int BM = 128, BN = 128, BK = 64, K = 768, LDA = 768, LDW = 768;
    __shared__ __hip_bfloat16 As[BM * BK];
    __shared__ __hip_bfloat16 Bs[BN * BK];
    const int tid = threadIdx.x;
    const int w = tid >> 6, l = tid & 63;
    const int wm = w >> 1, wn = w & 1;
    const int m0 = blockIdx.y * BM, n0 = blockIdx.x * BN;
    const bool isZ = (n0 < ZDIM);
    const __hip_bfloat16* W = isZ ? (W2b + (size_t)n0 * LDW) : (W3b + (size_t)(n0 - ZDIM) * LDW);
    const int lrow = l >> 3, lcol = (l & 7) * 8;

    f32x4 acc[4][4] = {};

    for (int kb = 0; kb < K; kb += BK) {
        __syncthreads();
        #pragma unroll
        for (int i = 0; i < 4; ++i) {
            int p = w * 4 + i;
            int rr = p * 8 + lrow;
            load16(A + (size_t)(m0 + rr) * LDA + kb + lcol, As + rr * BK + lcol);
        }
        #pragma unroll
        for (int i = 0; i < 4; ++i) {
            int p = w * 4 + i;
            int rr = p * 8 + lrow;
            load16(W + (size_t)rr * LDW + kb + lcol, Bs + rr * BK + lcol);
        }
        __builtin_amdgcn_s_waitcnt(0);
        __syncthreads();
        #pragma unroll
        for (int ks = 0; ks < BK; ks += 32) {
            bf16x8 af[4], bfr[4];
            #pragma unroll
            for (int i = 0; i < 4; ++i)
                af[i] = *(const bf16x8*)(const void*)(As + (wm * 64 + i * 16 + (l & 15)) * BK + ks + (l >> 4) * 8);
            #pragma unroll
            for (int j = 0; j < 4; ++j)
                bfr[j] = *(const bf16x8*)(const void*)(Bs + (wn * 64 + j * 16 + (l & 15)) * BK + ks + (l >> 4) * 8);
            #pragma unroll
            for (int i = 0; i < 4; ++i)
                #pragma unroll
                for (int j = 0; j < 4; ++j)
                    acc[i][j] = __builtin_amdgcn_mfma_f32_16x16x32_bf16(af[i], bfr[j], acc[i][j], 0, 0, 0);
        }
    }

    const float rdecay = (float)(0.2 * 4.0 / 32.0);
    #pragma unroll
    for (int j = 0; j < 4; ++j) {
        int col = n0 + wn * 64 + j * 16 + (l & 15);
        float bv = isZ ? b2[col] : b3[col - ZDIM];
        #pragma unroll
        for (int i = 0; i < 4; ++i) {
            int rbase = m0 + wm * 64 + i * 16 + (l >> 4) * 4;
            #pragma unroll
            for (int rg = 0; rg < 4; ++rg) {
                int row = rbase + rg;
                float v = lrelu(acc[i][j][rg] + bv) * rdecay;
                if (isZ) {
                    size_t idx = (size_t)row * ZDIM + col;
                    float zn = v + zs[idx];
                    zs[idx] = zn;
                    zb[idx] = __float2bfloat16(zn);
                    out[((size_t)row * TFRAMES + t) * ZDIM + col] = zn - z0[idx];
                } else {
                    int c2 = col - ZDIM;
                    size_t idx = (size_t)row * HDIM + c2;
                    float hn = v + hs[idx];
                    hs[idx] = hn;
                    tnext[(size_t)row * 768 + HDIM + c2] = __float2bfloat16(hn);
                }
            }
        }
    }
}

// ---------------- prep kernels ----------------
__global__ void cvt_kernel(const float* __restrict__ s, __hip_bfloat16* __restrict__ d, int n) {
    for (int i = blockIdx.x * blockDim.x + threadIdx.x; i < n; i += gridDim.x * blockDim.x)
        d[i] = __float2bfloat16(s[i]);
}

__global__ void h_to_temp_kernel(const float* __restrict__ h, __hip_bfloat16* __restrict__ temp, int n) {
    for (int i = blockIdx.x * blockDim.x + threadIdx.x; i < n; i += gridDim.x * blockDim.x) {
        int b = i / HDIM, j = i - b * HDIM;
        temp[(size_t)b * 768 + HDIM + j] = __float2bfloat16(h[i]);
    }
}

__global__ void zero_out0_kernel(float* __restrict__ out) {
    int n = B_ROWS * ZDIM;
    for (int i = blockIdx.x * blockDim.x + threadIdx.x; i < n; i += gridDim.x * blockDim.x) {
        int b = i >> 9, j = i & 511;
        out[(size_t)b * TFRAMES * ZDIM + j] = 0.f;
    }
}

extern "C" void kernel_launch(void* const* d_in, const int* in_sizes, int n_in,
                              void* d_out, int out_size, void* d_ws, size_t ws_size,
                              hipStream_t stream) {
    const float* z  = (const float*)d_in[0];
    const float* h0 = (const float*)d_in[1];
    const float* W1 = (const float*)d_in[2];
    const float* b1 = (const float*)d_in[3];
    const float* W2 = (const float*)d_in[4];
    const float* b2 = (const float*)d_in[5];
    const float* W3 = (const float*)d_in[6];
    const float* b3 = (const float*)d_in[7];
    float* out = (float*)d_out;

    char* p = (char*)d_ws;
    float* zs = (float*)p;              p += (size_t)B_ROWS * ZDIM * 4;     // 8 MB
    float* hs = (float*)p;              p += (size_t)B_ROWS * HDIM * 4;     // 6 MB
    __hip_bfloat16* zb    = (__hip_bfloat16*)p; p += (size_t)B_ROWS * ZDIM * 2;   // 4 MB
    __hip_bfloat16* temp0 = (__hip_bfloat16*)p; p += (size_t)B_ROWS * 768 * 2;    // 6 MB
    __hip_bfloat16* temp1 = (__hip_bfloat16*)p; p += (size_t)B_ROWS * 768 * 2;    // 6 MB
    __hip_bfloat16* W1b   = (__hip_bfloat16*)p; p += (size_t)HDIM * ZDIM * 2;
    __hip_bfloat16* W2b   = (__hip_bfloat16*)p; p += (size_t)ZDIM * 768 * 2;
    __hip_bfloat16* W3b   = (__hip_bfloat16*)p; p += (size_t)HDIM * 768 * 2;

    // init master states (fp32) and bf16 GEMM inputs
    hipMemcpyAsync(zs, z,  (size_t)B_ROWS * ZDIM * 4, hipMemcpyDeviceToDevice, stream);
    hipMemcpyAsync(hs, h0, (size_t)B_ROWS * HDIM * 4, hipMemcpyDeviceToDevice, stream);
    cvt_kernel<<<256, 256, 0, stream>>>(z, zb, B_ROWS * ZDIM);
    h_to_temp_kernel<<<256, 256, 0, stream>>>(h0, temp1, B_ROWS * HDIM);   // step 1 uses temp1
    cvt_kernel<<<64, 256, 0, stream>>>(W1, W1b, HDIM * ZDIM);
    cvt_kernel<<<128, 256, 0, stream>>>(W2, W2b, ZDIM * 768);
    cvt_kernel<<<96, 256, 0, stream>>>(W3, W3b, HDIM * 768);
    zero_out0_kernel<<<256, 256, 0, stream>>>(out);

    for (int t = 1; t < TFRAMES; ++t) {
        __hip_bfloat16* tcur  = (t & 1) ? temp1 : temp0;
        __hip_bfloat16* tnext = (t & 1) ? temp0 : temp1;
        // K1: temp_cur[:, 0:384] = bf16(lrelu(zb @ W1^T + b1))
        k1_gemm<<<dim3(HDIM / 128, B_ROWS / 64), 256, 0, stream>>>(zb, W1b, b1, tcur);
        // K2: z/h update + out write, h-part of temp_next for next step
        k2_gemm<<<dim3((ZDIM + HDIM) / 128, B_ROWS / 128), 256, 0, stream>>>(
            tcur, W2b, W3b, b2, b3, zs, hs, zb, tnext, z, out, t);
    }
}

// Round 2
// 1842.574 us; speedup vs baseline: 1.0885x; 1.0885x over previous
//
#include <hip/hip_runtime.h>
#include <type_traits>

// LatentRecurrent persistent kernel: B=4096, Z=512, H=384, T=32, r=0.025
// One block = 32 batch rows for ALL 31 steps. State in LDS:
//   zf   : z master fp32 [32][516]   (padded stride 516: 516%32==4 -> balanced banks)
//   tz   : lrelu(z@W1^T+b1) f16 [32][392]  (K-cols 0..383 of temp)
//   hb[2]: h f16 double-buffer [32][392]   (K-cols 384..767 of temp)
// Weights f16 in d_ws, streamed per step as MFMA B-fragments straight from L2.
// MFMA: 32x32x16 f16. A: lane m=l&31, k=(l>>5)*8+j. B: n=l&31, same k.
// C/D: col=lane&31, row=(reg&3)+8*(reg>>2)+4*(lane>>5)  [measured m74/m101]

typedef _Float16 f16;
typedef f16 f16x8 __attribute__((ext_vector_type(8)));
typedef float f32x4 __attribute__((ext_vector_type(4)));
typedef float f32x16 __attribute__((ext_vector_type(16)));

#define ZD 512
#define HD 384
#define TT 32
#define BM 32
#define LZ 516   // zf row stride (floats):  516 ≡ 4 (mod 32) -> conflict-balanced b128
#define LT 392   // tz/hb row stride (f16):  196 words ≡ 4 (mod 32) -> balanced, 16B-aligned rows

__device__ __forceinline__ float lrelu(float x) { return x >= 0.f ? x : 0.01f * x; }

__global__ void cvt_f32_f16(const float* __restrict__ s, f16* __restrict__ d, int n) {
    for (int i = blockIdx.x * blockDim.x + threadIdx.x; i < n; i += gridDim.x * blockDim.x)
        d[i] = (f16)s[i];
}

__global__ __launch_bounds__(512) void latrec(
    const float* __restrict__ z0g, const float* __restrict__ h0g,
    const f16* __restrict__ W1h, const f16* __restrict__ W2h, const f16* __restrict__ W3h,
    const float* __restrict__ b1g, const float* __restrict__ b2g, const float* __restrict__ b3g,
    float* __restrict__ out)
{
    __shared__ float zf[BM * LZ];
    __shared__ f16 tz[BM * LT];
    __shared__ f16 hb[2][BM * LT];
    __shared__ float bias[1280];   // b1 @0, b2 @384, b3 @896

    const int tid = threadIdx.x;
    const int w = tid >> 6, l = tid & 63;
    const int lm = l & 31;          // row (A) / col (B,C) within 32-tile
    const int lk = (l >> 5) * 8;    // k-offset of this lane's fragment
    const int m0 = blockIdx.x * BM;

    // ---- init: biases, z slice (fp32), h slice (f16), zero out[:,0,:] ----
    for (int i = tid; i < HD; i += 512) bias[i] = b1g[i];
    for (int i = tid; i < ZD; i += 512) bias[384 + i] = b2g[i];
    for (int i = tid; i < HD; i += 512) bias[896 + i] = b3g[i];
    for (int i = tid; i < BM * 128; i += 512) {
        int r = i >> 7, c = (i & 127) << 2;
        f32x4 v = *(const f32x4*)(z0g + (size_t)(m0 + r) * ZD + c);
        *(f32x4*)(zf + r * LZ + c) = v;
        f32x4 zr = {0.f, 0.f, 0.f, 0.f};
        __builtin_nontemporal_store(zr.x, out + ((size_t)(m0 + r) * TT) * ZD + c);
        __builtin_nontemporal_store(zr.y, out + ((size_t)(m0 + r) * TT) * ZD + c + 1);
        __builtin_nontemporal_store(zr.z, out + ((size_t)(m0 + r) * TT) * ZD + c + 2);
        __builtin_nontemporal_store(zr.w, out + ((size_t)(m0 + r) * TT) * ZD + c + 3);
    }
    for (int i = tid; i < BM * HD; i += 512) {
        int r = i / HD, c = i - r * HD;
        hb[0][r * LT + c] = (f16)h0g[(size_t)(m0 + r) * HD + c];
    }
    __syncthreads();

    for (int t = 1; t < TT; ++t) {
        const f16* hcur = hb[(t - 1) & 1];
        f16* hnxt = hb[t & 1];

        // ================= GEMM1: tz = f16(lrelu(z @ W1^T + b1)) =================
        // 12 n-tiles of 32: waves 0-3 take pair (2w,2w+1); waves 4-7 take single (w+4)
        {
            const int nt0 = (w < 4) ? 2 * w : (w + 4);
            const int nt1 = (w < 4) ? 2 * w + 1 : nt0;
            const float* ap = zf + lm * LZ + lk;
            const f16* wp0 = W1h + (size_t)(nt0 * 32 + lm) * ZD + lk;
            const f16* wp1 = W1h + (size_t)(nt1 * 32 + lm) * ZD + lk;
            auto run1 = [&](auto NTC) {
                constexpr int NT = decltype(NTC)::value;
                f32x16 a0 = {}, a1 = {};
                #pragma unroll 4
                for (int ks = 0; ks < ZD; ks += 16) {
                    f32x4 x0 = *(const f32x4*)(ap + ks);
                    f32x4 x1 = *(const f32x4*)(ap + ks + 4);
                    f16x8 af;
                    #pragma unroll
                    for (int e = 0; e < 4; ++e) { af[e] = (f16)x0[e]; af[4 + e] = (f16)x1[e]; }
                    f16x8 bf0 = *(const f16x8*)(wp0 + ks);
                    a0 = __builtin_amdgcn_mfma_f32_32x32x16_f16(af, bf0, a0, 0, 0, 0);
                    if constexpr (NT == 2) {
                        f16x8 bf1 = *(const f16x8*)(wp1 + ks);
                        a1 = __builtin_amdgcn_mfma_f32_32x32x16_f16(af, bf1, a1, 0, 0, 0);
                    }
                }
                {
                    int c = nt0 * 32 + lm; float bv = bias[c];
                    #pragma unroll
                    for (int rg = 0; rg < 16; ++rg) {
                        int row = (rg & 3) + 8 * (rg >> 2) + 4 * (l >> 5);
                        tz[row * LT + c] = (f16)lrelu(a0[rg] + bv);
                    }
                }
                if constexpr (NT == 2) {
                    int c = nt1 * 32 + lm; float bv = bias[c];
                    #pragma unroll
                    for (int rg = 0; rg < 16; ++rg) {
                        int row = (rg & 3) + 8 * (rg >> 2) + 4 * (l >> 5);
                        tz[row * LT + c] = (f16)lrelu(a1[rg] + bv);
                    }
                }
            };
            if (w < 4) run1(std::integral_constant<int, 2>{});
            else       run1(std::integral_constant<int, 1>{});
        }
        __syncthreads();

        // ======== GEMM2/3: fused over N=896 (16 z-tiles + 12 h-tiles), K=768 ========
        // wave w: tiles {w, w+8} (z) + {16+2w,17+2w} (w<4, h) or {20+w} (w>=4, h)
        {
            const int t0 = w, t1 = w + 8;
            const int t2 = (w < 4) ? 16 + 2 * w : 20 + w;
            const int t3 = (w < 4) ? 17 + 2 * w : t2;
            auto wptr = [&](int nt) {
                return (nt < 16) ? W2h + (size_t)(nt * 32 + lm) * 768 + lk
                                 : W3h + (size_t)((nt - 16) * 32 + lm) * 768 + lk;
            };
            const f16* wp0 = wptr(t0); const f16* wp1 = wptr(t1);
            const f16* wp2 = wptr(t2); const f16* wp3 = wptr(t3);
            const f16* ap1 = tz + lm * LT + lk;
            const f16* ap2 = hcur + lm * LT + lk;

            auto epi2 = [&](const f32x16& ac, int nt) {
                if (nt < 16) {  // z update + out write (wave-uniform branch)
                    int c = nt * 32 + lm;
                    float bv = bias[384 + c];
                    #pragma unroll
                    for (int rg = 0; rg < 16; ++rg) {
                        int row = (rg & 3) + 8 * (rg >> 2) + 4 * (l >> 5);
                        float v = lrelu(ac[rg] + bv) * 0.025f;
                        float zn = zf[row * LZ + c] + v;
                        zf[row * LZ + c] = zn;
                        size_t gr = (size_t)(m0 + row);
                        float o = zn - z0g[gr * ZD + c];
                        __builtin_nontemporal_store(o, out + (gr * TT + t) * ZD + c);
                    }
                } else {        // h update into next-step buffer
                    int c = (nt - 16) * 32 + lm;
                    float bv = bias[896 + c];
                    #pragma unroll
                    for (int rg = 0; rg < 16; ++rg) {
                        int row = (rg & 3) + 8 * (rg >> 2) + 4 * (l >> 5);
                        float v = lrelu(ac[rg] + bv) * 0.025f;
                        float hn = (float)hcur[row * LT + c] + v;
                        hnxt[row * LT + c] = (f16)hn;
                    }
                }
            };

            auto run2 = [&](auto NTC) {
                constexpr int NT = decltype(NTC)::value;
                f32x16 a0 = {}, a1 = {}, a2 = {}, a3 = {};
                auto khalf = [&](const f16* ab, int kw) {
                    #pragma unroll 4
                    for (int ks = 0; ks < HD; ks += 16) {
                        f16x8 af = *(const f16x8*)(ab + ks);
                        f16x8 b0 = *(const f16x8*)(wp0 + kw + ks);
                        a0 = __builtin_amdgcn_mfma_f32_32x32x16_f16(af, b0, a0, 0, 0, 0);
                        f16x8 b1 = *(const f16x8*)(wp1 + kw + ks);
                        a1 = __builtin_amdgcn_mfma_f32_32x32x16_f16(af, b1, a1, 0, 0, 0);
                        f16x8 b2 = *(const f16x8*)(wp2 + kw + ks);
                        a2 = __builtin_amdgcn_mfma_f32_32x32x16_f16(af, b2, a2, 0, 0, 0);
                        if constexpr (NT == 4) {
                            f16x8 b3 = *(const f16x8*)(wp3 + kw + ks);
                            a3 = __builtin_amdgcn_mfma_f32_32x32x16_f16(af, b3, a3, 0, 0, 0);
                        }
                    }
                };
                khalf(ap1, 0);    // K 0..383  from tz
                khalf(ap2, HD);   // K 384..767 from h buffer
                epi2(a0, t0); epi2(a1, t1); epi2(a2, t2);
                if constexpr (NT == 4) epi2(a3, t3);
            };
            if (w < 4) run2(std::integral_constant<int, 4>{});
            else       run2(std::integral_constant<int, 3>{});
        }
        __syncthreads();
    }
}

extern "C" void kernel_launch(void* const* d_in, const int* in_sizes, int n_in,
                              void* d_out, int out_size, void* d_ws, size_t ws_size,
                              hipStream_t stream) {
    const float* z  = (const float*)d_in[0];
    const float* h0 = (const float*)d_in[1];
    const float* W1 = (const float*)d_in[2];
    const float* b1 = (const float*)d_in[3];
    const float* W2 = (const float*)d_in[4];
    const float* b2 = (const float*)d_in[5];
    const float* W3 = (const float*)d_in[6];
    const float* b3 = (const float*)d_in[7];
    float* out = (float*)d_out;

    char* p = (char*)d_ws;
    f16* W1h = (f16*)p; p += (size_t)HD * ZD * 2;
    f16* W2h = (f16*)p; p += (size_t)ZD * 768 * 2;
    f16* W3h = (f16*)p; p += (size_t)HD * 768 * 2;

    cvt_f32_f16<<<96, 256, 0, stream>>>(W1, W1h, HD * ZD);
    cvt_f32_f16<<<192, 256, 0, stream>>>(W2, W2h, ZD * 768);
    cvt_f32_f16<<<144, 256, 0, stream>>>(W3, W3h, HD * 768);

    latrec<<<4096 / BM, 512, 0, stream>>>(z, h0, W1h, W2h, W3h, b1, b2, b3, out);
}